// Round 4
// baseline (1397.689 us; speedup 1.0000x reference)
//
#include <hip/hip_runtime.h>
#include <stdint.h>

#define DEV __device__ __forceinline__

typedef unsigned short u16;
typedef __attribute__((ext_vector_type(8))) short short8;
typedef __attribute__((ext_vector_type(4))) float floatx4;

#define B_ 2
#define T_ 1024
#define C_ 768
#define H_ 12
#define L_ 6
#define V_ 32000
#define F_ 3072
#define M_ 2048   // B*T
#define C3_ 2304  // 3*C (packed qkv)

#define VMW(n) asm volatile("s_waitcnt vmcnt(" #n ")" ::: "memory")

DEV u16 f2bf(float f) {
  unsigned int u; __builtin_memcpy(&u, &f, 4);
  u += 0x7FFFu + ((u >> 16) & 1u);   // round-to-nearest-even
  return (u16)(u >> 16);
}

// async global->LDS, 16B per lane. LDS ptr wave-uniform; HW adds lane*16.
DEV void gload16(const void* g, void* l) {
  __builtin_amdgcn_global_load_lds(
      (__attribute__((address_space(1))) void*)(uintptr_t)g,
      (__attribute__((address_space(3))) void*)(unsigned int)(uintptr_t)l,
      16, 0, 0);
}

// bijective XCD swizzle (m204)
DEV int xcd_swz(int flat, int nwg) {
  int q = nwg >> 3, r = nwg & 7;
  int xcd = flat & 7, sid = flat >> 3;
  return (xcd < r ? xcd * (q + 1) : r * (q + 1) + (xcd - r) * q) + sid;
}

// ---------------- transpose + f32->bf16 convert: src[z][R][Cc] -> dst[Cc][R] ----------------
__global__ __launch_bounds__(256) void transpose_f32_bf16(
    const float* __restrict__ src, u16* __restrict__ dst, int R, int Cc,
    size_t src_z, size_t dst_z) {
  __shared__ float tile[32][33];
  const float* s = src + (size_t)blockIdx.z * src_z;
  u16* d = dst + (size_t)blockIdx.z * dst_z;
  int c0 = blockIdx.x * 32, r0 = blockIdx.y * 32;
  int tx = threadIdx.x & 31, ty = threadIdx.x >> 5;
#pragma unroll
  for (int i = 0; i < 4; i++)
    tile[ty + 8 * i][tx] = s[(size_t)(r0 + ty + 8 * i) * Cc + (c0 + tx)];
  __syncthreads();
#pragma unroll
  for (int i = 0; i < 4; i++)
    d[(size_t)(c0 + ty + 8 * i) * R + (r0 + tx)] = f2bf(tile[tx][ty + 8 * i]);
}

// ---------------- embedding ----------------
__global__ __launch_bounds__(256) void embed_kernel(
    const int* __restrict__ idx, const float* __restrict__ tok,
    const float* __restrict__ pos, float* __restrict__ x) {
  int row = blockIdx.x;
  int t = row & (T_ - 1);
  int tk = idx[row];
  const float* tp = tok + (size_t)tk * C_;
  const float* pp = pos + (size_t)t * C_;
  float* xp = x + (size_t)row * C_;
  for (int c = threadIdx.x; c < C_; c += 256) xp[c] = tp[c] + pp[c];
}

// ---------------- layernorm: f32 in -> bf16 out ----------------
__global__ __launch_bounds__(256) void ln_kernel(
    const float* __restrict__ x, const float* __restrict__ g,
    const float* __restrict__ b, u16* __restrict__ out) {
  int row = blockIdx.x;
  int tid = threadIdx.x;
  const float* xp = x + (size_t)row * C_;
  float v0 = xp[tid], v1 = xp[tid + 256], v2 = xp[tid + 512];
  float s = v0 + v1 + v2;
  float ss = v0 * v0 + v1 * v1 + v2 * v2;
#pragma unroll
  for (int o = 32; o > 0; o >>= 1) { s += __shfl_down(s, o); ss += __shfl_down(ss, o); }
  __shared__ float red[8];
  int wid = tid >> 6;
  if ((tid & 63) == 0) { red[wid] = s; red[4 + wid] = ss; }
  __syncthreads();
  float tot = red[0] + red[1] + red[2] + red[3];
  float tss = red[4] + red[5] + red[6] + red[7];
  float mean = tot * (1.f / C_);
  float var = tss * (1.f / C_) - mean * mean;
  float rstd = rsqrtf(var + 1e-5f);
  u16* op = out + (size_t)row * C_;
  op[tid]       = f2bf((v0 - mean) * rstd * g[tid]       + b[tid]);
  op[tid + 256] = f2bf((v1 - mean) * rstd * g[tid + 256] + b[tid + 256]);
  op[tid + 512] = f2bf((v2 - mean) * rstd * g[tid + 512] + b[tid + 512]);
}

// ---------------- GEMM: A[M,K](bf16) @ BT[N,K](bf16), BK=32, 3-deep ring + counted vmcnt ----------------
// LDS per K-tile stored CHUNKED: [4 k-quarters][rows][16B] -> frag reads are bank-conflict-free
// (lanes 0-15 read 16 consecutive 16B blocks; each bank hit exactly 8x/wave = minimum).
// OUTMODE: 0 = bf16 out, 1 = f32 accumulate (atomic if SPLITK), 2 = f32 out,
//          3 = qkv mode (cols >= 1536 write V^T to vt[b*C+c][T], else bf16 to ob)
template <int THREADS, int BM, int BN, int BIAS, int RELU, int OUTMODE, int SPLITK>
__global__ __launch_bounds__(THREADS) void gemm3(
    const u16* __restrict__ A, const u16* __restrict__ BT,
    const float* __restrict__ bias,
    u16* __restrict__ ob, float* __restrict__ fout, u16* __restrict__ vt,
    int N, int K) {
  constexpr int ALOADS = (BM * 64) / (THREADS * 16);
  constexpr int BLOADS = (BN * 64) / (THREADS * 16);
  constexpr int LDS_L = ALOADS + BLOADS;
  __shared__ __align__(16) u16 As[3][BM * 32];
  __shared__ __align__(16) u16 Bs[3][BN * 32];

  int tid = threadIdx.x;
  int lane = tid & 63, w = tid >> 6;
  int wm = w >> 1, wn = w & 1;
  int rr = lane & 15, qg = lane >> 4;

  int gx = gridDim.x;
  int nwg = gx * gridDim.y;
  int flat = blockIdx.y * gx + blockIdx.x;
  int wg = xcd_swz(flat, nwg);
  int m0 = (wg % gx) * BM, n0 = (wg / gx) * BN;

  int kz = SPLITK ? blockIdx.z : 0;
  int Keff = SPLITK ? (K >> 1) : K;
  int kbase = kz * Keff;

  // per-thread staging sources: LDS byte d -> (chunk = d/(BM*16), row = (d%(BM*16))>>4)
  const u16* Aps[ALOADS];
  const u16* Bps[BLOADS];
#pragma unroll
  for (int i = 0; i < ALOADS; i++) {
    int d = (i * THREADS + tid) * 16;
    int chunk = d / (BM * 16);
    int row = (d % (BM * 16)) >> 4;
    Aps[i] = A + (size_t)(m0 + row) * K + chunk * 8 + kbase;
  }
#pragma unroll
  for (int i = 0; i < BLOADS; i++) {
    int d = (i * THREADS + tid) * 16;
    int chunk = d / (BN * 16);
    int row = (d % (BN * 16)) >> 4;
    Bps[i] = BT + (size_t)(n0 + row) * K + chunk * 8 + kbase;
  }

  auto stage = [&](int sl, int kk) {
#pragma unroll
    for (int i = 0; i < ALOADS; i++)
      gload16(Aps[i] + kk, (char*)As + (size_t)sl * BM * 64 + i * THREADS * 16 + w * 1024);
#pragma unroll
    for (int i = 0; i < BLOADS; i++)
      gload16(Bps[i] + kk, (char*)Bs + (size_t)sl * BN * 64 + i * THREADS * 16 + w * 1024);
  };

  floatx4 zero = {0.f, 0.f, 0.f, 0.f};
  floatx4 acc[4][4];
#pragma unroll
  for (int i = 0; i < 4; i++)
#pragma unroll
    for (int j = 0; j < 4; j++) acc[i][j] = zero;

  int NT = Keff >> 5;
  stage(0, 0);
  stage(1, 32);
  if constexpr (LDS_L == 3) VMW(3); else VMW(4);
  __builtin_amdgcn_s_barrier();
  __builtin_amdgcn_sched_barrier(0);

  for (int t = 0; t < NT; ++t) {
    int sl = t % 3;
    if (t + 2 < NT) stage((t + 2) % 3, (t + 2) << 5);
    __builtin_amdgcn_sched_barrier(0);
    const char* Ab = (const char*)As + (size_t)sl * BM * 64;
    const char* Bb = (const char*)Bs + (size_t)sl * BN * 64;
    short8 af[4], bf[4];
#pragma unroll
    for (int i = 0; i < 4; i++) {
      af[i] = *(const short8*)(Ab + qg * (BM * 16) + (wm * 64 + i * 16 + rr) * 16);
      bf[i] = *(const short8*)(Bb + qg * (BN * 16) + (wn * 64 + i * 16 + rr) * 16);
    }
    __builtin_amdgcn_s_setprio(1);
#pragma unroll
    for (int i = 0; i < 4; i++)
#pragma unroll
      for (int j = 0; j < 4; j++)
        acc[i][j] = __builtin_amdgcn_mfma_f32_16x16x32_bf16(af[i], bf[j], acc[i][j], 0, 0, 0);
    __builtin_amdgcn_s_setprio(0);
    if (t < NT - 2) { if constexpr (LDS_L == 3) VMW(3); else VMW(4); }
    else if (t == NT - 2) VMW(0);
    if (t < NT - 1) { __builtin_amdgcn_s_barrier(); __builtin_amdgcn_sched_barrier(0); }
  }

  int cb = n0 + wn * 64;
  int rb = m0 + wm * 64;
  bool isv = (OUTMODE == 3) && (n0 >= 1536);
#pragma unroll
  for (int i = 0; i < 4; i++) {
#pragma unroll
    for (int j = 0; j < 4; j++) {
      int col = cb + j * 16 + rr;
      float bv = 0.f;
      if (BIAS && kz == 0) bv = bias[col];
      float vals[4];
#pragma unroll
      for (int r = 0; r < 4; r++) {
        float val = acc[i][j][r] + bv;
        if (RELU) val = fmaxf(val, 0.f);
        vals[r] = val;
      }
      int row0 = rb + i * 16 + qg * 4;
      if (isv) {
        int colv = col - 1536;
        int bb = row0 >> 10, t0 = row0 & (T_ - 1);
        uint2 pk;
        pk.x = (unsigned int)f2bf(vals[0]) | ((unsigned int)f2bf(vals[1]) << 16);
        pk.y = (unsigned int)f2bf(vals[2]) | ((unsigned int)f2bf(vals[3]) << 16);
        *(uint2*)&vt[((size_t)bb * C_ + colv) * T_ + t0] = pk;
      } else {
#pragma unroll
        for (int r = 0; r < 4; r++) {
          size_t o = (size_t)(row0 + r) * N + col;
          if (OUTMODE == 0 || OUTMODE == 3) ob[o] = f2bf(vals[r]);
          else if (OUTMODE == 1) {
            if (SPLITK) atomicAdd(&fout[o], vals[r]);
            else fout[o] += vals[r];
          } else fout[o] = vals[r];
        }
      }
    }
  }
}

// ---------------- fused causal attention, swapped-QK^T, lane-local softmax ----------------
// 1 wave per 16 query rows. Q/K from packed qkv (row stride C3_); V^T in vt[b*C+c][T].
__global__ __launch_bounds__(64) void attn_kernel(
    const u16* __restrict__ qkv, const u16* __restrict__ vt, u16* __restrict__ o) {
  __shared__ __align__(16) u16 P_s[16 * 48];
  int nwg = gridDim.x;
  int wg = xcd_swz(blockIdx.x, nwg);
  int qt = wg & 63;
  int h = (wg >> 6) % H_;
  int b = wg / (64 * H_);
  int q0 = qt << 4;
  int lane = threadIdx.x;
  int rr = lane & 15, qg = lane >> 4, kq = qg << 3;

  const u16* qb = qkv + (size_t)(b * T_ + q0 + rr) * C3_ + h * 64;
  short8 qf0 = *(const short8*)(qb + kq);
  short8 qf1 = *(const short8*)(qb + 32 + kq);

  float m_r = -1e30f, l_r = 0.f;
  floatx4 zero = {0.f, 0.f, 0.f, 0.f};
  floatx4 oacc[4];
#pragma unroll
  for (int d = 0; d < 4; d++) oacc[d] = zero;

  const u16* kbase = qkv + (size_t)(b * T_) * C3_ + 768 + h * 64;
  const u16* vbase = vt + (size_t)(b * C_ + h * 64) * T_;

  for (int kt0 = 0; kt0 <= q0 + 15; kt0 += 32) {
    floatx4 s[2];
#pragma unroll
    for (int c = 0; c < 2; c++) {
      const u16* kb = kbase + (size_t)(kt0 + c * 16 + rr) * C3_;
      short8 kf0 = *(const short8*)(kb + kq);
      short8 kf1 = *(const short8*)(kb + 32 + kq);
      floatx4 z = zero;
      z = __builtin_amdgcn_mfma_f32_16x16x32_bf16(kf0, qf0, z, 0, 0, 0);
      z = __builtin_amdgcn_mfma_f32_16x16x32_bf16(kf1, qf1, z, 0, 0, 0);
      s[c] = z;
    }
    int qpos = q0 + rr;
    float p[2][4];
    float mx = -1e30f;
#pragma unroll
    for (int c = 0; c < 2; c++)
#pragma unroll
      for (int r = 0; r < 4; r++) {
        int kpos = kt0 + c * 16 + qg * 4 + r;
        float val = s[c][r] * 0.125f;
        val = (kpos <= qpos) ? val : -1e30f;
        p[c][r] = val;
        mx = fmaxf(mx, val);
      }
    mx = fmaxf(mx, __shfl_xor(mx, 16));
    mx = fmaxf(mx, __shfl_xor(mx, 32));
    float mn = fmaxf(m_r, mx);
    float escL = exp2f((m_r - mn) * 1.44269504f);
    m_r = mn;
    float ps = 0.f;
#pragma unroll
    for (int c = 0; c < 2; c++)
#pragma unroll
      for (int r = 0; r < 4; r++) {
        float pv = exp2f((p[c][r] - mn) * 1.44269504f);
        p[c][r] = pv;
        ps += pv;
      }
    ps += __shfl_xor(ps, 16);
    ps += __shfl_xor(ps, 32);
    l_r = l_r * escL + ps;
#pragma unroll
    for (int c = 0; c < 2; c++) {
      unsigned int u0 = (unsigned int)f2bf(p[c][0]) | ((unsigned int)f2bf(p[c][1]) << 16);
      unsigned int u1 = (unsigned int)f2bf(p[c][2]) | ((unsigned int)f2bf(p[c][3]) << 16);
      uint2 pk; pk.x = u0; pk.y = u1;
      *(uint2*)&P_s[rr * 48 + c * 16 + qg * 4] = pk;
    }
    float er[4];
#pragma unroll
    for (int r = 0; r < 4; r++) er[r] = __shfl(escL, qg * 4 + r);
#pragma unroll
    for (int d = 0; d < 4; d++)
#pragma unroll
      for (int r = 0; r < 4; r++) oacc[d][r] *= er[r];
    short8 pa = *(const short8*)&P_s[rr * 48 + kq];
#pragma unroll
    for (int d = 0; d < 4; d++) {
      short8 vf = *(const short8*)(vbase + (size_t)(d * 16 + rr) * T_ + kt0 + kq);
      oacc[d] = __builtin_amdgcn_mfma_f32_16x16x32_bf16(pa, vf, oacc[d], 0, 0, 0);
    }
  }
  float lb[4];
#pragma unroll
  for (int r = 0; r < 4; r++) lb[r] = __shfl(l_r, qg * 4 + r);
  u16* obp = o + (size_t)(b * T_ + q0) * C_ + h * 64;
#pragma unroll
  for (int d = 0; d < 4; d++)
#pragma unroll
    for (int r = 0; r < 4; r++) {
      int row = qg * 4 + r;
      obp[(size_t)row * C_ + d * 16 + rr] = f2bf(oacc[d][r] / lb[r]);
    }
}

extern "C" void kernel_launch(void* const* d_in, const int* in_sizes, int n_in,
                              void* d_out, int out_size, void* d_ws, size_t ws_size,
                              hipStream_t stream) {
  (void)in_sizes; (void)n_in; (void)out_size; (void)ws_size;
  const int*   xidx = (const int*)d_in[0];
  const float* tok  = (const float*)d_in[1];
  const float* pos  = (const float*)d_in[2];
  const float* ln1g = (const float*)d_in[3];
  const float* ln1b = (const float*)d_in[4];
  const float* wq   = (const float*)d_in[5];
  const float* wk   = (const float*)d_in[6];
  const float* wv   = (const float*)d_in[7];
  const float* wo   = (const float*)d_in[8];
  const float* bo   = (const float*)d_in[9];
  const float* ln2g = (const float*)d_in[10];
  const float* ln2b = (const float*)d_in[11];
  const float* w1   = (const float*)d_in[12];
  const float* b1   = (const float*)d_in[13];
  const float* w2   = (const float*)d_in[14];
  const float* b2   = (const float*)d_in[15];
  const float* lnfg = (const float*)d_in[16];
  const float* lnfb = (const float*)d_in[17];
  const float* wp   = (const float*)d_in[18];
  const float* bp   = (const float*)d_in[19];

  char* ws = (char*)d_ws;
  size_t off = 0;
  auto alloc = [&](size_t bytes) { char* p = ws + off; off += (bytes + 255) & ~(size_t)255; return p; };
  u16* wqkvT = (u16*)alloc((size_t)L_ * 3 * C_ * C_ * 2);   // [l][3C][C]
  u16* woT = (u16*)alloc((size_t)L_ * C_ * C_ * 2);
  u16* w1T = (u16*)alloc((size_t)L_ * C_ * F_ * 2);
  u16* w2T = (u16*)alloc((size_t)L_ * C_ * F_ * 2);
  u16* wpT = (u16*)alloc((size_t)C_ * V_ * 2);
  float* x = (float*)alloc((size_t)M_ * C_ * 4);
  u16* hb   = (u16*)alloc((size_t)M_ * C_ * 2);
  u16* qkvb = (u16*)alloc((size_t)M_ * C3_ * 2);
  u16* vtb  = (u16*)alloc((size_t)M_ * C_ * 2);
  u16* aob  = (u16*)alloc((size_t)M_ * C_ * 2);
  u16* mb   = (u16*)alloc((size_t)M_ * F_ * 2);

  dim3 blk(256);
  size_t CC = (size_t)C_ * C_, CF = (size_t)C_ * F_;
  transpose_f32_bf16<<<dim3(C_ / 32, C_ / 32, L_), blk, 0, stream>>>(wq, wqkvT,          C_, C_, CC, 3 * CC);
  transpose_f32_bf16<<<dim3(C_ / 32, C_ / 32, L_), blk, 0, stream>>>(wk, wqkvT + CC,     C_, C_, CC, 3 * CC);
  transpose_f32_bf16<<<dim3(C_ / 32, C_ / 32, L_), blk, 0, stream>>>(wv, wqkvT + 2 * CC, C_, C_, CC, 3 * CC);
  transpose_f32_bf16<<<dim3(C_ / 32, C_ / 32, L_), blk, 0, stream>>>(wo, woT, C_, C_, CC, CC);
  transpose_f32_bf16<<<dim3(F_ / 32, C_ / 32, L_), blk, 0, stream>>>(w1, w1T, C_, F_, CF, CF);
  transpose_f32_bf16<<<dim3(C_ / 32, F_ / 32, L_), blk, 0, stream>>>(w2, w2T, F_, C_, CF, CF);
  transpose_f32_bf16<<<dim3(V_ / 32, C_ / 32, 1), blk, 0, stream>>>(wp, wpT, C_, V_, 0, 0);
  embed_kernel<<<M_, blk, 0, stream>>>(xidx, tok, pos, x);

  for (int l = 0; l < L_; ++l) {
    size_t wOff = (size_t)l * 3 * CC;
    size_t oOff = (size_t)l * CC;
    size_t fOff = (size_t)l * CF;
    ln_kernel<<<M_, blk, 0, stream>>>(x, ln1g + l * C_, ln1b + l * C_, hb);
    gemm3<256, 128, 128, 0, 0, 3, 0><<<dim3(M_ / 128, C3_ / 128), 256, 0, stream>>>(
        hb, wqkvT + wOff, nullptr, qkvb, nullptr, vtb, C3_, C_);
    attn_kernel<<<B_ * H_ * (T_ / 16), dim3(64), 0, stream>>>(qkvb, vtb, aob);
    gemm3<256, 128, 128, 1, 0, 1, 1><<<dim3(M_ / 128, C_ / 128, 2), 256, 0, stream>>>(
        aob, woT + oOff, bo + l * C_, nullptr, x, nullptr, C_, C_);
    ln_kernel<<<M_, blk, 0, stream>>>(x, ln2g + l * C_, ln2b + l * C_, hb);
    gemm3<256, 128, 128, 1, 1, 0, 0><<<dim3(M_ / 128, F_ / 128), 256, 0, stream>>>(
        hb, w1T + fOff, b1 + l * F_, mb, nullptr, nullptr, F_, C_);
    gemm3<256, 128, 128, 1, 0, 1, 1><<<dim3(M_ / 128, C_ / 128, 2), 256, 0, stream>>>(
        mb, w2T + fOff, b2 + l * C_, nullptr, x, nullptr, C_, F_);
  }
  ln_kernel<<<M_, blk, 0, stream>>>(x, lnfg, lnfb, hb);
  gemm3<512, 256, 128, 1, 0, 2, 0><<<dim3(M_ / 256, V_ / 128), 512, 0, stream>>>(
      hb, wpT, bp, nullptr, (float*)d_out, nullptr, V_, C_);
}

// Round 5
// 1073.896 us; speedup vs baseline: 1.3015x; 1.3015x over previous
//
#include <hip/hip_runtime.h>
#include <stdint.h>

#define DEV __device__ __forceinline__

typedef unsigned short u16;
typedef __attribute__((ext_vector_type(8))) short short8;
typedef __attribute__((ext_vector_type(4))) float floatx4;

#define B_ 2
#define T_ 1024
#define C_ 768
#define H_ 12
#define L_ 6
#define V_ 32000
#define F_ 3072
#define M_ 2048   // B*T
#define C3_ 2304  // 3*C (packed qkv)

#define VMW(n) asm volatile("s_waitcnt vmcnt(" #n ")" ::: "memory")

DEV u16 f2bf(float f) {
  unsigned int u; __builtin_memcpy(&u, &f, 4);
  u += 0x7FFFu + ((u >> 16) & 1u);   // round-to-nearest-even
  return (u16)(u >> 16);
}

// async global->LDS, 16B per lane. LDS ptr wave-uniform; HW adds lane*16.
DEV void gload16(const void* g, void* l) {
  __builtin_amdgcn_global_load_lds(
      (__attribute__((address_space(1))) void*)(uintptr_t)g,
      (__attribute__((address_space(3))) void*)(unsigned int)(uintptr_t)l,
      16, 0, 0);
}

// bijective XCD swizzle (m204)
DEV int xcd_swz(int flat, int nwg) {
  int q = nwg >> 3, r = nwg & 7;
  int xcd = flat & 7, sid = flat >> 3;
  return (xcd < r ? xcd * (q + 1) : r * (q + 1) + (xcd - r) * q) + sid;
}

// ---------------- transpose + f32->bf16 convert: src[z][R][Cc] -> dst[Cc][R] ----------------
__global__ __launch_bounds__(256) void transpose_f32_bf16(
    const float* __restrict__ src, u16* __restrict__ dst, int R, int Cc,
    size_t src_z, size_t dst_z) {
  __shared__ float tile[32][33];
  const float* s = src + (size_t)blockIdx.z * src_z;
  u16* d = dst + (size_t)blockIdx.z * dst_z;
  int c0 = blockIdx.x * 32, r0 = blockIdx.y * 32;
  int tx = threadIdx.x & 31, ty = threadIdx.x >> 5;
#pragma unroll
  for (int i = 0; i < 4; i++)
    tile[ty + 8 * i][tx] = s[(size_t)(r0 + ty + 8 * i) * Cc + (c0 + tx)];
  __syncthreads();
#pragma unroll
  for (int i = 0; i < 4; i++)
    d[(size_t)(c0 + ty + 8 * i) * R + (r0 + tx)] = f2bf(tile[tx][ty + 8 * i]);
}

// ---------------- embedding ----------------
__global__ __launch_bounds__(256) void embed_kernel(
    const int* __restrict__ idx, const float* __restrict__ tok,
    const float* __restrict__ pos, float* __restrict__ x) {
  int row = blockIdx.x;
  int t = row & (T_ - 1);
  int tk = idx[row];
  const float* tp = tok + (size_t)tk * C_;
  const float* pp = pos + (size_t)t * C_;
  float* xp = x + (size_t)row * C_;
  for (int c = threadIdx.x; c < C_; c += 256) xp[c] = tp[c] + pp[c];
}

// ---------------- layernorm: f32 in -> bf16 out ----------------
__global__ __launch_bounds__(256) void ln_kernel(
    const float* __restrict__ x, const float* __restrict__ g,
    const float* __restrict__ b, u16* __restrict__ out) {
  int row = blockIdx.x;
  int tid = threadIdx.x;
  const float* xp = x + (size_t)row * C_;
  float v0 = xp[tid], v1 = xp[tid + 256], v2 = xp[tid + 512];
  float s = v0 + v1 + v2;
  float ss = v0 * v0 + v1 * v1 + v2 * v2;
#pragma unroll
  for (int o = 32; o > 0; o >>= 1) { s += __shfl_down(s, o); ss += __shfl_down(ss, o); }
  __shared__ float red[8];
  int wid = tid >> 6;
  if ((tid & 63) == 0) { red[wid] = s; red[4 + wid] = ss; }
  __syncthreads();
  float tot = red[0] + red[1] + red[2] + red[3];
  float tss = red[4] + red[5] + red[6] + red[7];
  float mean = tot * (1.f / C_);
  float var = tss * (1.f / C_) - mean * mean;
  float rstd = rsqrtf(var + 1e-5f);
  u16* op = out + (size_t)row * C_;
  op[tid]       = f2bf((v0 - mean) * rstd * g[tid]       + b[tid]);
  op[tid + 256] = f2bf((v1 - mean) * rstd * g[tid + 256] + b[tid + 256]);
  op[tid + 512] = f2bf((v2 - mean) * rstd * g[tid + 512] + b[tid + 512]);
}

// ---------------- GEMM: A[M,K](bf16) @ BT[N,K](bf16), BK=32, 3-deep ring + counted vmcnt ----------------
// LDS row-major [row][64B], 16B-slot swizzle: slot = chunk ^ ((row>>1)&3).
// Staging: coalesced 64B/row with pre-permuted chunk source; frag read XORs the same mask ->
// 8 even bank passes per wave b128 (2 lanes/slot = free). Rule #21 both-sides-consistent.
// OUTMODE: 0 = bf16 out, 1 = f32 accumulate (atomic if SPLITK), 2 = f32 out,
//          3 = qkv mode (cols >= 1536 write V^T to vt[b*C+c][T], else bf16 to ob)
template <int THREADS, int BM, int BN, int BIAS, int RELU, int OUTMODE, int SPLITK>
__global__ __launch_bounds__(THREADS) void gemm3(
    const u16* __restrict__ A, const u16* __restrict__ BT,
    const float* __restrict__ bias,
    u16* __restrict__ ob, float* __restrict__ fout, u16* __restrict__ vt,
    int N, int K) {
  constexpr int ALOADS = (BM * 64) / (THREADS * 16);
  constexpr int BLOADS = (BN * 64) / (THREADS * 16);
  constexpr int LDS_L = ALOADS + BLOADS;
  __shared__ __align__(16) u16 As[3][BM * 32];
  __shared__ __align__(16) u16 Bs[3][BN * 32];

  int tid = threadIdx.x;
  int lane = tid & 63, w = tid >> 6;
  int wm = w >> 1, wn = w & 1;
  int rr = lane & 15, qg = lane >> 4;

  int gx = gridDim.x;
  int nwg = gx * gridDim.y;
  int flat = blockIdx.y * gx + blockIdx.x;
  int wg = xcd_swz(flat, nwg);
  int m0 = (wg % gx) * BM, n0 = (wg / gx) * BN;

  int kz = SPLITK ? blockIdx.z : 0;
  int Keff = SPLITK ? (K >> 1) : K;
  int kbase = kz * Keff;

  // staging source: LDS 16B-slot index (i*THREADS+tid) -> row = idx>>2, s = idx&3,
  // holds global chunk = s ^ ((row>>1)&3)
  const u16* Aps[ALOADS];
  const u16* Bps[BLOADS];
#pragma unroll
  for (int i = 0; i < ALOADS; i++) {
    int idx = i * THREADS + tid;
    int row = idx >> 2;
    int chunk = (idx & 3) ^ ((row >> 1) & 3);
    Aps[i] = A + (size_t)(m0 + row) * K + chunk * 8 + kbase;
  }
#pragma unroll
  for (int i = 0; i < BLOADS; i++) {
    int idx = i * THREADS + tid;
    int row = idx >> 2;
    int chunk = (idx & 3) ^ ((row >> 1) & 3);
    Bps[i] = BT + (size_t)(n0 + row) * K + chunk * 8 + kbase;
  }

  auto stage = [&](int sl, int kk) {
#pragma unroll
    for (int i = 0; i < ALOADS; i++)
      gload16(Aps[i] + kk, (char*)As + (size_t)sl * BM * 64 + i * THREADS * 16 + w * 1024);
#pragma unroll
    for (int i = 0; i < BLOADS; i++)
      gload16(Bps[i] + kk, (char*)Bs + (size_t)sl * BN * 64 + i * THREADS * 16 + w * 1024);
  };

  floatx4 zero = {0.f, 0.f, 0.f, 0.f};
  floatx4 acc[4][4];
#pragma unroll
  for (int i = 0; i < 4; i++)
#pragma unroll
    for (int j = 0; j < 4; j++) acc[i][j] = zero;

  int NT = Keff >> 5;
  stage(0, 0);
  stage(1, 32);
  if constexpr (LDS_L == 3) VMW(3); else VMW(4);
  __builtin_amdgcn_s_barrier();
  __builtin_amdgcn_sched_barrier(0);

  // fragment slot swizzle: independent of i (i*16>>1 ≡ 0 mod 4)
  int sqA = (qg ^ ((rr >> 1) & 3)) << 4;

  for (int t = 0; t < NT; ++t) {
    int sl = t % 3;
    if (t + 2 < NT) stage((t + 2) % 3, (t + 2) << 5);
    __builtin_amdgcn_sched_barrier(0);
    const char* Ab = (const char*)As + (size_t)sl * BM * 64;
    const char* Bb = (const char*)Bs + (size_t)sl * BN * 64;
    short8 af[4], bf[4];
#pragma unroll
    for (int i = 0; i < 4; i++) {
      af[i] = *(const short8*)(Ab + ((wm * 64 + i * 16 + rr) << 6) + sqA);
      bf[i] = *(const short8*)(Bb + ((wn * 64 + i * 16 + rr) << 6) + sqA);
    }
    __builtin_amdgcn_s_setprio(1);
#pragma unroll
    for (int i = 0; i < 4; i++)
#pragma unroll
      for (int j = 0; j < 4; j++)
        acc[i][j] = __builtin_amdgcn_mfma_f32_16x16x32_bf16(af[i], bf[j], acc[i][j], 0, 0, 0);
    __builtin_amdgcn_s_setprio(0);
    if (t < NT - 2) { if constexpr (LDS_L == 3) VMW(3); else VMW(4); }
    else if (t == NT - 2) VMW(0);
    if (t < NT - 1) { __builtin_amdgcn_s_barrier(); __builtin_amdgcn_sched_barrier(0); }
  }

  int cb = n0 + wn * 64;
  int rb = m0 + wm * 64;
  bool isv = (OUTMODE == 3) && (n0 >= 1536);
#pragma unroll
  for (int i = 0; i < 4; i++) {
#pragma unroll
    for (int j = 0; j < 4; j++) {
      int col = cb + j * 16 + rr;
      float bv = 0.f;
      if (BIAS && kz == 0) bv = bias[col];
      float vals[4];
#pragma unroll
      for (int r = 0; r < 4; r++) {
        float val = acc[i][j][r] + bv;
        if (RELU) val = fmaxf(val, 0.f);
        vals[r] = val;
      }
      int row0 = rb + i * 16 + qg * 4;
      if (isv) {
        int colv = col - 1536;
        int bb = row0 >> 10, t0 = row0 & (T_ - 1);
        uint2 pk;
        pk.x = (unsigned int)f2bf(vals[0]) | ((unsigned int)f2bf(vals[1]) << 16);
        pk.y = (unsigned int)f2bf(vals[2]) | ((unsigned int)f2bf(vals[3]) << 16);
        *(uint2*)&vt[((size_t)bb * C_ + colv) * T_ + t0] = pk;
      } else {
#pragma unroll
        for (int r = 0; r < 4; r++) {
          size_t o = (size_t)(row0 + r) * N + col;
          if (OUTMODE == 0 || OUTMODE == 3) ob[o] = f2bf(vals[r]);
          else if (OUTMODE == 1) {
            if (SPLITK) atomicAdd(&fout[o], vals[r]);
            else fout[o] += vals[r];
          } else fout[o] = vals[r];
        }
      }
    }
  }
}

// ---------------- fused causal attention, swapped-QK^T, lane-local softmax ----------------
// 1 wave per 16 query rows. Q/K from packed qkv (row stride C3_); V^T in vt[b*C+c][T].
__global__ __launch_bounds__(64) void attn_kernel(
    const u16* __restrict__ qkv, const u16* __restrict__ vt, u16* __restrict__ o) {
  __shared__ __align__(16) u16 P_s[16 * 48];
  int nwg = gridDim.x;
  int wg = xcd_swz(blockIdx.x, nwg);
  int qt = wg & 63;
  int h = (wg >> 6) % H_;
  int b = wg / (64 * H_);
  int q0 = qt << 4;
  int lane = threadIdx.x;
  int rr = lane & 15, qg = lane >> 4, kq = qg << 3;

  const u16* qb = qkv + (size_t)(b * T_ + q0 + rr) * C3_ + h * 64;
  short8 qf0 = *(const short8*)(qb + kq);
  short8 qf1 = *(const short8*)(qb + 32 + kq);

  float m_r = -1e30f, l_r = 0.f;
  floatx4 zero = {0.f, 0.f, 0.f, 0.f};
  floatx4 oacc[4];
#pragma unroll
  for (int d = 0; d < 4; d++) oacc[d] = zero;

  const u16* kbase = qkv + (size_t)(b * T_) * C3_ + 768 + h * 64;
  const u16* vbase = vt + (size_t)(b * C_ + h * 64) * T_;

  for (int kt0 = 0; kt0 <= q0 + 15; kt0 += 32) {
    floatx4 s[2];
#pragma unroll
    for (int c = 0; c < 2; c++) {
      const u16* kb = kbase + (size_t)(kt0 + c * 16 + rr) * C3_;
      short8 kf0 = *(const short8*)(kb + kq);
      short8 kf1 = *(const short8*)(kb + 32 + kq);
      floatx4 z = zero;
      z = __builtin_amdgcn_mfma_f32_16x16x32_bf16(kf0, qf0, z, 0, 0, 0);
      z = __builtin_amdgcn_mfma_f32_16x16x32_bf16(kf1, qf1, z, 0, 0, 0);
      s[c] = z;
    }
    int qpos = q0 + rr;
    float p[2][4];
    float mx = -1e30f;
#pragma unroll
    for (int c = 0; c < 2; c++)
#pragma unroll
      for (int r = 0; r < 4; r++) {
        int kpos = kt0 + c * 16 + qg * 4 + r;
        float val = s[c][r] * 0.125f;
        val = (kpos <= qpos) ? val : -1e30f;
        p[c][r] = val;
        mx = fmaxf(mx, val);
      }
    mx = fmaxf(mx, __shfl_xor(mx, 16));
    mx = fmaxf(mx, __shfl_xor(mx, 32));
    float mn = fmaxf(m_r, mx);
    float escL = exp2f((m_r - mn) * 1.44269504f);
    m_r = mn;
    float ps = 0.f;
#pragma unroll
    for (int c = 0; c < 2; c++)
#pragma unroll
      for (int r = 0; r < 4; r++) {
        float pv = exp2f((p[c][r] - mn) * 1.44269504f);
        p[c][r] = pv;
        ps += pv;
      }
    ps += __shfl_xor(ps, 16);
    ps += __shfl_xor(ps, 32);
    l_r = l_r * escL + ps;
#pragma unroll
    for (int c = 0; c < 2; c++) {
      unsigned int u0 = (unsigned int)f2bf(p[c][0]) | ((unsigned int)f2bf(p[c][1]) << 16);
      unsigned int u1 = (unsigned int)f2bf(p[c][2]) | ((unsigned int)f2bf(p[c][3]) << 16);
      uint2 pk; pk.x = u0; pk.y = u1;
      *(uint2*)&P_s[rr * 48 + c * 16 + qg * 4] = pk;
    }
    float er[4];
#pragma unroll
    for (int r = 0; r < 4; r++) er[r] = __shfl(escL, qg * 4 + r);
#pragma unroll
    for (int d = 0; d < 4; d++)
#pragma unroll
      for (int r = 0; r < 4; r++) oacc[d][r] *= er[r];
    short8 pa = *(const short8*)&P_s[rr * 48 + kq];
#pragma unroll
    for (int d = 0; d < 4; d++) {
      short8 vf = *(const short8*)(vbase + (size_t)(d * 16 + rr) * T_ + kt0 + kq);
      oacc[d] = __builtin_amdgcn_mfma_f32_16x16x32_bf16(pa, vf, oacc[d], 0, 0, 0);
    }
  }
  float lb[4];
#pragma unroll
  for (int r = 0; r < 4; r++) lb[r] = __shfl(l_r, qg * 4 + r);
  u16* obp = o + (size_t)(b * T_ + q0) * C_ + h * 64;
#pragma unroll
  for (int d = 0; d < 4; d++)
#pragma unroll
    for (int r = 0; r < 4; r++) {
      int row = qg * 4 + r;
      obp[(size_t)row * C_ + d * 16 + rr] = f2bf(oacc[d][r] / lb[r]);
    }
}

extern "C" void kernel_launch(void* const* d_in, const int* in_sizes, int n_in,
                              void* d_out, int out_size, void* d_ws, size_t ws_size,
                              hipStream_t stream) {
  (void)in_sizes; (void)n_in; (void)out_size; (void)ws_size;
  const int*   xidx = (const int*)d_in[0];
  const float* tok  = (const float*)d_in[1];
  const float* pos  = (const float*)d_in[2];
  const float* ln1g = (const float*)d_in[3];
  const float* ln1b = (const float*)d_in[4];
  const float* wq   = (const float*)d_in[5];
  const float* wk   = (const float*)d_in[6];
  const float* wv   = (const float*)d_in[7];
  const float* wo   = (const float*)d_in[8];
  const float* bo   = (const float*)d_in[9];
  const float* ln2g = (const float*)d_in[10];
  const float* ln2b = (const float*)d_in[11];
  const float* w1   = (const float*)d_in[12];
  const float* b1   = (const float*)d_in[13];
  const float* w2   = (const float*)d_in[14];
  const float* b2   = (const float*)d_in[15];
  const float* lnfg = (const float*)d_in[16];
  const float* lnfb = (const float*)d_in[17];
  const float* wp   = (const float*)d_in[18];
  const float* bp   = (const float*)d_in[19];

  char* ws = (char*)d_ws;
  size_t off = 0;
  auto alloc = [&](size_t bytes) { char* p = ws + off; off += (bytes + 255) & ~(size_t)255; return p; };
  u16* wqkvT = (u16*)alloc((size_t)L_ * 3 * C_ * C_ * 2);   // [l][3C][C]
  u16* woT = (u16*)alloc((size_t)L_ * C_ * C_ * 2);
  u16* w1T = (u16*)alloc((size_t)L_ * C_ * F_ * 2);
  u16* w2T = (u16*)alloc((size_t)L_ * C_ * F_ * 2);
  u16* wpT = (u16*)alloc((size_t)C_ * V_ * 2);
  float* x = (float*)alloc((size_t)M_ * C_ * 4);
  u16* hb   = (u16*)alloc((size_t)M_ * C_ * 2);
  u16* qkvb = (u16*)alloc((size_t)M_ * C3_ * 2);
  u16* vtb  = (u16*)alloc((size_t)M_ * C_ * 2);
  u16* aob  = (u16*)alloc((size_t)M_ * C_ * 2);
  u16* mb   = (u16*)alloc((size_t)M_ * F_ * 2);

  dim3 blk(256);
  size_t CC = (size_t)C_ * C_, CF = (size_t)C_ * F_;
  transpose_f32_bf16<<<dim3(C_ / 32, C_ / 32, L_), blk, 0, stream>>>(wq, wqkvT,          C_, C_, CC, 3 * CC);
  transpose_f32_bf16<<<dim3(C_ / 32, C_ / 32, L_), blk, 0, stream>>>(wk, wqkvT + CC,     C_, C_, CC, 3 * CC);
  transpose_f32_bf16<<<dim3(C_ / 32, C_ / 32, L_), blk, 0, stream>>>(wv, wqkvT + 2 * CC, C_, C_, CC, 3 * CC);
  transpose_f32_bf16<<<dim3(C_ / 32, C_ / 32, L_), blk, 0, stream>>>(wo, woT, C_, C_, CC, CC);
  transpose_f32_bf16<<<dim3(F_ / 32, C_ / 32, L_), blk, 0, stream>>>(w1, w1T, C_, F_, CF, CF);
  transpose_f32_bf16<<<dim3(C_ / 32, F_ / 32, L_), blk, 0, stream>>>(w2, w2T, F_, C_, CF, CF);
  transpose_f32_bf16<<<dim3(V_ / 32, C_ / 32, 1), blk, 0, stream>>>(wp, wpT, C_, V_, 0, 0);
  embed_kernel<<<M_, blk, 0, stream>>>(xidx, tok, pos, x);

  for (int l = 0; l < L_; ++l) {
    size_t wOff = (size_t)l * 3 * CC;
    size_t oOff = (size_t)l * CC;
    size_t fOff = (size_t)l * CF;
    ln_kernel<<<M_, blk, 0, stream>>>(x, ln1g + l * C_, ln1b + l * C_, hb);
    gemm3<256, 128, 128, 0, 0, 3, 0><<<dim3(M_ / 128, C3_ / 128), 256, 0, stream>>>(
        hb, wqkvT + wOff, nullptr, qkvb, nullptr, vtb, C3_, C_);
    attn_kernel<<<B_ * H_ * (T_ / 16), dim3(64), 0, stream>>>(qkvb, vtb, aob);
    gemm3<256, 128, 128, 1, 0, 1, 1><<<dim3(M_ / 128, C_ / 128, 2), 256, 0, stream>>>(
        aob, woT + oOff, bo + l * C_, nullptr, x, nullptr, C_, C_);
    ln_kernel<<<M_, blk, 0, stream>>>(x, ln2g + l * C_, ln2b + l * C_, hb);
    gemm3<256, 128, 128, 1, 1, 0, 0><<<dim3(M_ / 128, F_ / 128), 256, 0, stream>>>(
        hb, w1T + fOff, b1 + l * F_, mb, nullptr, nullptr, F_, C_);
    gemm3<256, 128, 128, 1, 0, 1, 1><<<dim3(M_ / 128, C_ / 128, 2), 256, 0, stream>>>(
        mb, w2T + fOff, b2 + l * C_, nullptr, x, nullptr, C_, F_);
  }
  ln_kernel<<<M_, blk, 0, stream>>>(x, lnfg, lnfb, hb);
  gemm3<512, 256, 128, 1, 0, 2, 0><<<dim3(M_ / 256, V_ / 128), 512, 0, stream>>>(
      hb, wpT, bp, nullptr, (float*)d_out, nullptr, V_, C_);
}